// Round 3
// baseline (46328.152 us; speedup 1.0000x reference)
//
#include <hip/hip_runtime.h>
#include <math.h>

#define DN 2048
#define NT 128

#define KB    8      // k-split count for W@A parts
#define KLEN  256    // k per block
#define CB    256    // cols per block
#define RB    32     // rows per block (4 waves x 8 rows)

constexpr float LR    = 1e-3f;
constexpr float BETA1 = 0.9f;
constexpr float BETA2 = 0.999f;
constexpr float EPSA  = 1e-8f;

__device__ __forceinline__ float f4get(const float4& v, int k) {
    return k == 0 ? v.x : (k == 1 ? v.y : (k == 2 ? v.z : v.w));
}

// ---------------------------------------------------------------------------
// Steady-state W@A partial matmul.
// parts[kb][row][col] = sum_{k in kb-slice} W[row][k] * A[k][col]
// Per-wave rows (wave-uniform W -> s_load on SMEM pipe), A in LDS.
// grid (DN/CB=8, NT/RB=4, KB=8), block 256 (4 waves).
__global__ __launch_bounds__(256)
void wa_kernel(const float* __restrict__ W, const float* __restrict__ A,
               float* __restrict__ parts)
{
    __shared__ __align__(16) float At[KLEN / 2][CB];   // 128 KiB
    const int colb  = blockIdx.x * CB;
    const int rowb  = blockIdx.y * RB;
    const int kb    = blockIdx.z;
    const int kbase = kb * KLEN;
    const int tx    = threadIdx.x;
    const int lane  = tx & 63;
    const int wid   = __builtin_amdgcn_readfirstlane(tx >> 6);  // wave id 0..3
    const int row0  = rowb + wid * 8;

    // wave-uniform row pointers -> scalar loads
    const float* wrow[8];
    #pragma unroll
    for (int r = 0; r < 8; ++r)
        wrow[r] = W + (size_t)(row0 + r) * DN + kbase;

    float4 acc[8];
    #pragma unroll
    for (int r = 0; r < 8; ++r) acc[r] = {0.f, 0.f, 0.f, 0.f};

    for (int half = 0; half < 2; ++half) {
        __syncthreads();   // protect previous At contents until all waves done
        {
            // stage At[k][c] = A[kbase + half*128 + k][colb + c], 128 x 256 fp32
            const float* src = A + (size_t)(kbase + half * (KLEN / 2)) * DN + colb;
            #pragma unroll 8
            for (int it = 0; it < 32; ++it) {
                const int f  = it * 256 + tx;   // flat float4 index
                const int kr = f >> 6;          // 64 float4 per k-row
                const int c4 = f & 63;
                *(float4*)&At[kr][c4 * 4] =
                    *(const float4*)&src[(size_t)kr * DN + c4 * 4];
            }
        }
        __syncthreads();

        const int hb = half * (KLEN / 2);
        #pragma unroll 4
        for (int kc = 0; kc < 32; ++kc) {
            float4 wv[8];
            #pragma unroll
            for (int r = 0; r < 8; ++r)
                wv[r] = *(const float4*)(wrow[r] + hb + 4 * kc);   // uniform -> s_load
            #pragma unroll
            for (int kk = 0; kk < 4; ++kk) {
                const float4 av = *(const float4*)&At[4 * kc + kk][lane * 4];
                #pragma unroll
                for (int r = 0; r < 8; ++r) {
                    const float wk = f4get(wv[r], kk);
                    acc[r].x += wk * av.x; acc[r].y += wk * av.y;
                    acc[r].z += wk * av.z; acc[r].w += wk * av.w;
                }
            }
        }
    }

    float* op = parts + (size_t)kb * (NT * DN);
    #pragma unroll
    for (int r = 0; r < 8; ++r)
        *(float4*)&op[(size_t)(row0 + r) * DN + colb + lane * 4] = acc[r];
}

// ---------------------------------------------------------------------------
// One-time precompute kernels (off steady-state path) — unchanged from R0.
// B-partials: out_parts[kb][i][j] = sum_k H[i][k]*Ht[j][k]  (k-slices of 512)
__global__ __launch_bounds__(512)
void bpart_kernel(const float* __restrict__ L, const float* __restrict__ R,
                  float* __restrict__ out_parts)
{
    __shared__ __align__(16) float Ws[128][36];
    __shared__ __align__(16) float At[32][36];
    const int j0    = blockIdx.x * 32;
    const int kbase = blockIdx.y * 512;
    const int tx = threadIdx.x;
    const int cg = tx & 7;
    const int rg = tx >> 3;
    float4 acc0 = {0.f, 0.f, 0.f, 0.f};
    float4 acc1 = {0.f, 0.f, 0.f, 0.f};

    for (int s = 0; s < 16; ++s) {
        const int k0 = kbase + s * 32;
        {
            int idx = tx;
            #pragma unroll
            for (int rr = 0; rr < 2; ++rr) {
                const int row = idx >> 3, f = idx & 7;
                const float4 wv = *(const float4*)&L[row * DN + k0 + 4 * f];
                *(float4*)&Ws[row][4 * f] = wv;
                idx += 512;
            }
            if (tx < 256) {
                const int c = tx >> 3, f = tx & 7;
                const float4 av = *(const float4*)&R[(size_t)(j0 + c) * DN + k0 + 4 * f];
                At[4 * f + 0][c] = av.x;
                At[4 * f + 1][c] = av.y;
                At[4 * f + 2][c] = av.z;
                At[4 * f + 3][c] = av.w;
            }
        }
        __syncthreads();
        #pragma unroll
        for (int kq = 0; kq < 8; ++kq) {
            const float4 w0 = *(const float4*)&Ws[rg][4 * kq];
            const float4 w1 = *(const float4*)&Ws[rg + 64][4 * kq];
            #pragma unroll
            for (int kk = 0; kk < 4; ++kk) {
                const float4 av = *(const float4*)&At[4 * kq + kk][4 * cg];
                const float wa = f4get(w0, kk);
                const float wb = f4get(w1, kk);
                acc0.x += wa * av.x; acc0.y += wa * av.y;
                acc0.z += wa * av.z; acc0.w += wa * av.w;
                acc1.x += wb * av.x; acc1.y += wb * av.y;
                acc1.z += wb * av.z; acc1.w += wb * av.w;
            }
        }
        __syncthreads();
    }
    float* op = out_parts + (size_t)blockIdx.y * (NT * DN);
    *(float4*)&op[rg * DN + j0 + 4 * cg] = acc0;
    *(float4*)&op[(rg + 64) * DN + j0 + 4 * cg] = acc1;
}

// A = Ht @ Ht^T
__global__ __launch_bounds__(256)
void gram_kernel(const float* __restrict__ Ht, float* __restrict__ A)
{
    __shared__ __align__(16) float Ti[64][36];
    __shared__ __align__(16) float Tj[64][36];
    const int i0 = blockIdx.x * 64, j0 = blockIdx.y * 64;
    const int tx = threadIdx.x;
    const int ti = tx & 15;
    const int tj = tx >> 4;
    float4 acc[4];
    #pragma unroll
    for (int a = 0; a < 4; ++a) acc[a] = {0.f, 0.f, 0.f, 0.f};

    for (int s = 0; s < 64; ++s) {
        const int k0 = s * 32;
        {
            int idx = tx;
            #pragma unroll
            for (int rr = 0; rr < 2; ++rr) {
                const int row = idx >> 3, f = idx & 7;
                *(float4*)&Ti[row][4 * f] = *(const float4*)&Ht[(size_t)(i0 + row) * DN + k0 + 4 * f];
                *(float4*)&Tj[row][4 * f] = *(const float4*)&Ht[(size_t)(j0 + row) * DN + k0 + 4 * f];
                idx += 256;
            }
        }
        __syncthreads();
        #pragma unroll
        for (int kq = 0; kq < 8; ++kq) {
            float4 iv[4], jv[4];
            #pragma unroll
            for (int a = 0; a < 4; ++a) iv[a] = *(const float4*)&Ti[ti + 16 * a][4 * kq];
            #pragma unroll
            for (int b = 0; b < 4; ++b) jv[b] = *(const float4*)&Tj[4 * tj + b][4 * kq];
            #pragma unroll
            for (int kk = 0; kk < 4; ++kk) {
                #pragma unroll
                for (int a = 0; a < 4; ++a) {
                    const float wa = f4get(iv[a], kk);
                    acc[a].x += wa * f4get(jv[0], kk);
                    acc[a].y += wa * f4get(jv[1], kk);
                    acc[a].z += wa * f4get(jv[2], kk);
                    acc[a].w += wa * f4get(jv[3], kk);
                }
            }
        }
        __syncthreads();
    }
    #pragma unroll
    for (int a = 0; a < 4; ++a)
        *(float4*)&A[(size_t)(i0 + ti + 16 * a) * DN + j0 + 4 * tj] = acc[a];
}

__global__ void sumB_kernel(const float* __restrict__ parts, float* __restrict__ Bm)
{
    const int idx = (blockIdx.x * 256 + threadIdx.x) * 4;
    float4 a = *(const float4*)&parts[idx];
    const float4 b = *(const float4*)&parts[(size_t)NT * DN + idx];
    const float4 c = *(const float4*)&parts[(size_t)2 * NT * DN + idx];
    const float4 d = *(const float4*)&parts[(size_t)3 * NT * DN + idx];
    a.x += b.x; a.x += c.x; a.x += d.x;
    a.y += b.y; a.y += c.y; a.y += d.y;
    a.z += b.z; a.z += c.z; a.z += d.z;
    a.w += b.w; a.w += c.w; a.w += d.w;
    *(float4*)&Bm[idx] = a;
}

__global__ void init_kernel(float* __restrict__ P, float* __restrict__ M,
                            float* __restrict__ V, float* __restrict__ W)
{
    const int idx = (blockIdx.x * 256 + threadIdx.x) * 4;
    const float4 z = {0.f, 0.f, 0.f, 0.f};
    const float u = 1.f / (float)DN;
    const float4 uu = {u, u, u, u};
    *(float4*)&P[idx] = z;
    *(float4*)&M[idx] = z;
    *(float4*)&V[idx] = z;
    *(float4*)&W[idx] = uu;
}

// ---------------------------------------------------------------------------
__device__ __forceinline__ float blk_sum(float x) {
    #pragma unroll
    for (int o = 32; o > 0; o >>= 1) x += __shfl_down(x, o);
    __shared__ float r[4];
    const int tx = threadIdx.x;
    if ((tx & 63) == 0) r[tx >> 6] = x;
    __syncthreads();
    x = (r[0] + r[1]) + (r[2] + r[3]);
    __syncthreads();
    return x;
}

__device__ __forceinline__ float blk_max(float x) {
    #pragma unroll
    for (int o = 32; o > 0; o >>= 1) x = fmaxf(x, __shfl_down(x, o));
    __shared__ float r[4];
    const int tx = threadIdx.x;
    if ((tx & 63) == 0) r[tx >> 6] = x;
    __syncthreads();
    x = fmaxf(fmaxf(r[0], r[1]), fmaxf(r[2], r[3]));
    __syncthreads();
    return x;
}

// One row: sum parts -> G, softmax VJP, Adam update, next softmax.
// grid 128, block 256 (8 cols/thread).
__global__ __launch_bounds__(256)
void adam_kernel(const float* __restrict__ parts, const float* __restrict__ Bm,
                 float* __restrict__ W, float* __restrict__ P,
                 float* __restrict__ M, float* __restrict__ V,
                 const float bc1, const float bc2)
{
    const int i = blockIdx.x;
    const int tx = threadIdx.x;
    const int base = i * DN + tx * 8;

    float G8[8], W8[8], P8[8], M8[8], V8[8], E8[8];
    {
        float4 s0 = {0.f, 0.f, 0.f, 0.f}, s1 = {0.f, 0.f, 0.f, 0.f};
        #pragma unroll
        for (int p = 0; p < KB; ++p) {
            const float4 x = *(const float4*)&parts[(size_t)p * (NT * DN) + base];
            const float4 y = *(const float4*)&parts[(size_t)p * (NT * DN) + base + 4];
            s0.x += x.x; s0.y += x.y; s0.z += x.z; s0.w += x.w;
            s1.x += y.x; s1.y += y.y; s1.z += y.z; s1.w += y.w;
        }
        const float4 b0 = *(const float4*)&Bm[base];
        const float4 b1 = *(const float4*)&Bm[base + 4];
        G8[0] = 2.f * (s0.x - b0.x); G8[1] = 2.f * (s0.y - b0.y);
        G8[2] = 2.f * (s0.z - b0.z); G8[3] = 2.f * (s0.w - b0.w);
        G8[4] = 2.f * (s1.x - b1.x); G8[5] = 2.f * (s1.y - b1.y);
        G8[6] = 2.f * (s1.z - b1.z); G8[7] = 2.f * (s1.w - b1.w);
    }
    *(float4*)&W8[0] = *(const float4*)&W[base];
    *(float4*)&W8[4] = *(const float4*)&W[base + 4];

    float sp = 0.f;
    #pragma unroll
    for (int e = 0; e < 8; ++e) sp += W8[e] * G8[e];
    const float srow = blk_sum(sp);

    *(float4*)&P8[0] = *(const float4*)&P[base];
    *(float4*)&P8[4] = *(const float4*)&P[base + 4];
    *(float4*)&M8[0] = *(const float4*)&M[base];
    *(float4*)&M8[4] = *(const float4*)&M[base + 4];
    *(float4*)&V8[0] = *(const float4*)&V[base];
    *(float4*)&V8[4] = *(const float4*)&V[base + 4];

    float mx = -1e30f;
    #pragma unroll
    for (int e = 0; e < 8; ++e) {
        const float g  = W8[e] * (G8[e] - srow);
        const float m_ = BETA1 * M8[e] + (1.f - BETA1) * g;
        const float v_ = BETA2 * V8[e] + (1.f - BETA2) * g * g;
        M8[e] = m_; V8[e] = v_;
        const float mh = m_ * bc1;
        const float vh = v_ * bc2;
        const float pn = P8[e] - LR * mh / (sqrtf(vh) + EPSA);
        P8[e] = pn;
        mx = fmaxf(mx, pn);
    }
    mx = blk_max(mx);

    float es = 0.f;
    #pragma unroll
    for (int e = 0; e < 8; ++e) { E8[e] = expf(P8[e] - mx); es += E8[e]; }
    const float sig = blk_sum(es);
    #pragma unroll
    for (int e = 0; e < 8; ++e) W8[e] = E8[e] / sig;

    *(float4*)&W[base]     = *(const float4*)&W8[0];
    *(float4*)&W[base + 4] = *(const float4*)&W8[4];
    *(float4*)&P[base]     = *(const float4*)&P8[0];
    *(float4*)&P[base + 4] = *(const float4*)&P8[4];
    *(float4*)&M[base]     = *(const float4*)&M8[0];
    *(float4*)&M[base + 4] = *(const float4*)&M8[4];
    *(float4*)&V[base]     = *(const float4*)&V8[0];
    *(float4*)&V[base + 4] = *(const float4*)&V8[4];
}

// ---------------------------------------------------------------------------
extern "C" void kernel_launch(void* const* d_in, const int* in_sizes, int n_in,
                              void* d_out, int out_size, void* d_ws, size_t ws_size,
                              hipStream_t stream)
{
    const float* H  = (const float*)d_in[0];   // [128][2048]
    const float* Ht = (const float*)d_in[1];   // [2048][2048]

    float* ws = (float*)d_ws;
    float* A     = ws;                          // 2048*2048        (16 MB)
    float* Bm    = A  + (size_t)DN * DN;        // 128*2048
    float* P     = Bm + (size_t)NT * DN;
    float* M     = P  + (size_t)NT * DN;
    float* V     = M  + (size_t)NT * DN;
    float* W     = V  + (size_t)NT * DN;
    float* parts = W  + (size_t)NT * DN;        // KB * 128*2048    (8 MB)

    // One-time precompute
    gram_kernel<<<dim3(32, 32), 256, 0, stream>>>(Ht, A);            // A = Ht Ht^T
    bpart_kernel<<<dim3(64, 4), 512, 0, stream>>>(H, Ht, parts);     // H Ht^T partials (4 slices)
    sumB_kernel<<<256, 256, 0, stream>>>(parts, Bm);                 // B = H Ht^T
    init_kernel<<<256, 256, 0, stream>>>(P, M, V, W);                // P=m=v=0, W=1/2048

    double b1t = 1.0, b2t = 1.0;
    for (int t = 1; t <= 1000; ++t) {
        b1t *= 0.9; b2t *= 0.999;
        wa_kernel<<<dim3(DN / CB, NT / RB, KB), 256, 0, stream>>>(W, A, parts);
        const float bc1 = (float)(1.0 / (1.0 - b1t));
        const float bc2 = (float)(1.0 / (1.0 - b2t));
        adam_kernel<<<NT, 256, 0, stream>>>(parts, Bm, W, P, M, V, bc1, bc2);
    }

    hipMemcpyAsync(d_out, W, (size_t)NT * DN * sizeof(float),
                   hipMemcpyDeviceToDevice, stream);
}

// Round 4
// 28144.595 us; speedup vs baseline: 1.6461x; 1.6461x over previous
//
#include <hip/hip_runtime.h>
#include <math.h>

#define DN 2048
#define NT 128

#define KS   16     // k-split count for W@A parts
#define KSL  128    // k per block (KS * KSL == DN)
#define KCH  32     // k per LDS stage chunk
#define CB   256    // cols per block
#define RB   32     // rows per block (4 waves x 8 rows)

constexpr float LR    = 1e-3f;
constexpr float BETA1 = 0.9f;
constexpr float BETA2 = 0.999f;
constexpr float EPSA  = 1e-8f;

__device__ __forceinline__ float f4get(const float4& v, int k) {
    return k == 0 ? v.x : (k == 1 ? v.y : (k == 2 ? v.z : v.w));
}

// ---------------------------------------------------------------------------
// Steady-state W@A partial matmul.
// parts[kb][row][col] = sum_{k in kb-slice} W[row][k] * A[k][col]
// 8 rows per wave (wave-uniform W -> s_load, SMEM pipe); A chunk in LDS (32 KiB).
// grid (DN/CB=8, NT/RB=4, KS=16) = 512 blocks, block 256 (4 waves) -> 2 blocks/CU.
__global__ __launch_bounds__(256)
void wa_kernel(const float* __restrict__ W, const float* __restrict__ A,
               float* __restrict__ parts)
{
    __shared__ __align__(16) float At[KCH][CB];   // 32 KiB
    const int colb  = blockIdx.x * CB;
    const int rowb  = blockIdx.y * RB;
    const int kb    = blockIdx.z;
    const int kbase = kb * KSL;
    const int tx    = threadIdx.x;
    const int lane  = tx & 63;
    const int wid   = __builtin_amdgcn_readfirstlane(tx >> 6);  // wave id 0..3
    const int row0  = rowb + wid * 8;

    const float* wbase = W + (size_t)row0 * DN + kbase;   // wave-uniform

    float4 acc[8];
    #pragma unroll
    for (int r = 0; r < 8; ++r) acc[r] = {0.f, 0.f, 0.f, 0.f};

    #pragma unroll 1
    for (int ch = 0; ch < KSL / KCH; ++ch) {          // 4 chunks of 32 k
        __syncthreads();   // protect previous chunk until all waves done
        {
            const float* src = A + (size_t)(kbase + ch * KCH) * DN + colb;
            #pragma unroll
            for (int it = 0; it < 8; ++it) {
                const int f  = it * 256 + tx;   // flat float4 idx, 0..2047
                const int kr = f >> 6;          // 64 float4 per k-row
                const int c4 = f & 63;
                *(float4*)&At[kr][c4 * 4] =
                    *(const float4*)&src[(size_t)kr * DN + c4 * 4];
            }
        }
        __syncthreads();

        #pragma unroll
        for (int kc = 0; kc < KCH / 4; ++kc) {        // 8 iters of 4 k
            float4 wv[8];
            #pragma unroll
            for (int r = 0; r < 8; ++r)               // wave-uniform -> s_load_x4
                wv[r] = *(const float4*)(wbase + (size_t)r * DN + ch * KCH + kc * 4);
            #pragma unroll
            for (int kk = 0; kk < 4; ++kk) {
                const float4 av = *(const float4*)&At[4 * kc + kk][lane * 4];
                #pragma unroll
                for (int r = 0; r < 8; ++r) {
                    const float wk = f4get(wv[r], kk);
                    acc[r].x += wk * av.x; acc[r].y += wk * av.y;
                    acc[r].z += wk * av.z; acc[r].w += wk * av.w;
                }
            }
        }
    }

    float* op = parts + (size_t)kb * (NT * DN);
    #pragma unroll
    for (int r = 0; r < 8; ++r)
        *(float4*)&op[(size_t)(row0 + r) * DN + colb + lane * 4] = acc[r];
}

// ---------------------------------------------------------------------------
// One-time precompute kernels (off steady-state path).
// B-partials: out_parts[kb][i][j] = sum_k H[i][k]*Ht[j][k]  (k-slices of 512)
__global__ __launch_bounds__(512)
void bpart_kernel(const float* __restrict__ L, const float* __restrict__ R,
                  float* __restrict__ out_parts)
{
    __shared__ __align__(16) float Ws[128][36];
    __shared__ __align__(16) float At[32][36];
    const int j0    = blockIdx.x * 32;
    const int kbase = blockIdx.y * 512;
    const int tx = threadIdx.x;
    const int cg = tx & 7;
    const int rg = tx >> 3;
    float4 acc0 = {0.f, 0.f, 0.f, 0.f};
    float4 acc1 = {0.f, 0.f, 0.f, 0.f};

    for (int s = 0; s < 16; ++s) {
        const int k0 = kbase + s * 32;
        {
            int idx = tx;
            #pragma unroll
            for (int rr = 0; rr < 2; ++rr) {
                const int row = idx >> 3, f = idx & 7;
                const float4 wv = *(const float4*)&L[row * DN + k0 + 4 * f];
                *(float4*)&Ws[row][4 * f] = wv;
                idx += 512;
            }
            if (tx < 256) {
                const int c = tx >> 3, f = tx & 7;
                const float4 av = *(const float4*)&R[(size_t)(j0 + c) * DN + k0 + 4 * f];
                At[4 * f + 0][c] = av.x;
                At[4 * f + 1][c] = av.y;
                At[4 * f + 2][c] = av.z;
                At[4 * f + 3][c] = av.w;
            }
        }
        __syncthreads();
        #pragma unroll
        for (int kq = 0; kq < 8; ++kq) {
            const float4 w0 = *(const float4*)&Ws[rg][4 * kq];
            const float4 w1 = *(const float4*)&Ws[rg + 64][4 * kq];
            #pragma unroll
            for (int kk = 0; kk < 4; ++kk) {
                const float4 av = *(const float4*)&At[4 * kq + kk][4 * cg];
                const float wa = f4get(w0, kk);
                const float wb = f4get(w1, kk);
                acc0.x += wa * av.x; acc0.y += wa * av.y;
                acc0.z += wa * av.z; acc0.w += wa * av.w;
                acc1.x += wb * av.x; acc1.y += wb * av.y;
                acc1.z += wb * av.z; acc1.w += wb * av.w;
            }
        }
        __syncthreads();
    }
    float* op = out_parts + (size_t)blockIdx.y * (NT * DN);
    *(float4*)&op[rg * DN + j0 + 4 * cg] = acc0;
    *(float4*)&op[(rg + 64) * DN + j0 + 4 * cg] = acc1;
}

// A = Ht @ Ht^T
__global__ __launch_bounds__(256)
void gram_kernel(const float* __restrict__ Ht, float* __restrict__ A)
{
    __shared__ __align__(16) float Ti[64][36];
    __shared__ __align__(16) float Tj[64][36];
    const int i0 = blockIdx.x * 64, j0 = blockIdx.y * 64;
    const int tx = threadIdx.x;
    const int ti = tx & 15;
    const int tj = tx >> 4;
    float4 acc[4];
    #pragma unroll
    for (int a = 0; a < 4; ++a) acc[a] = {0.f, 0.f, 0.f, 0.f};

    for (int s = 0; s < 64; ++s) {
        const int k0 = s * 32;
        {
            int idx = tx;
            #pragma unroll
            for (int rr = 0; rr < 2; ++rr) {
                const int row = idx >> 3, f = idx & 7;
                *(float4*)&Ti[row][4 * f] = *(const float4*)&Ht[(size_t)(i0 + row) * DN + k0 + 4 * f];
                *(float4*)&Tj[row][4 * f] = *(const float4*)&Ht[(size_t)(j0 + row) * DN + k0 + 4 * f];
                idx += 256;
            }
        }
        __syncthreads();
        #pragma unroll
        for (int kq = 0; kq < 8; ++kq) {
            float4 iv[4], jv[4];
            #pragma unroll
            for (int a = 0; a < 4; ++a) iv[a] = *(const float4*)&Ti[ti + 16 * a][4 * kq];
            #pragma unroll
            for (int b = 0; b < 4; ++b) jv[b] = *(const float4*)&Tj[4 * tj + b][4 * kq];
            #pragma unroll
            for (int kk = 0; kk < 4; ++kk) {
                #pragma unroll
                for (int a = 0; a < 4; ++a) {
                    const float wa = f4get(iv[a], kk);
                    acc[a].x += wa * f4get(jv[0], kk);
                    acc[a].y += wa * f4get(jv[1], kk);
                    acc[a].z += wa * f4get(jv[2], kk);
                    acc[a].w += wa * f4get(jv[3], kk);
                }
            }
        }
        __syncthreads();
    }
    #pragma unroll
    for (int a = 0; a < 4; ++a)
        *(float4*)&A[(size_t)(i0 + ti + 16 * a) * DN + j0 + 4 * tj] = acc[a];
}

__global__ void sumB_kernel(const float* __restrict__ parts, float* __restrict__ Bm)
{
    const int idx = (blockIdx.x * 256 + threadIdx.x) * 4;
    float4 a = *(const float4*)&parts[idx];
    const float4 b = *(const float4*)&parts[(size_t)NT * DN + idx];
    const float4 c = *(const float4*)&parts[(size_t)2 * NT * DN + idx];
    const float4 d = *(const float4*)&parts[(size_t)3 * NT * DN + idx];
    a.x += b.x; a.x += c.x; a.x += d.x;
    a.y += b.y; a.y += c.y; a.y += d.y;
    a.z += b.z; a.z += c.z; a.z += d.z;
    a.w += b.w; a.w += c.w; a.w += d.w;
    *(float4*)&Bm[idx] = a;
}

__global__ void init_kernel(float* __restrict__ P, float* __restrict__ M,
                            float* __restrict__ V, float* __restrict__ W)
{
    const int idx = (blockIdx.x * 256 + threadIdx.x) * 4;
    const float4 z = {0.f, 0.f, 0.f, 0.f};
    const float u = 1.f / (float)DN;
    const float4 uu = {u, u, u, u};
    *(float4*)&P[idx] = z;
    *(float4*)&M[idx] = z;
    *(float4*)&V[idx] = z;
    *(float4*)&W[idx] = uu;
}

// ---------------------------------------------------------------------------
// Block reductions for 512 threads (8 waves).
__device__ __forceinline__ float blk_sum(float x) {
    #pragma unroll
    for (int o = 32; o > 0; o >>= 1) x += __shfl_down(x, o);
    __shared__ float r[8];
    const int tx = threadIdx.x;
    if ((tx & 63) == 0) r[tx >> 6] = x;
    __syncthreads();
    x = ((r[0] + r[1]) + (r[2] + r[3])) + ((r[4] + r[5]) + (r[6] + r[7]));
    __syncthreads();
    return x;
}

__device__ __forceinline__ float blk_max(float x) {
    #pragma unroll
    for (int o = 32; o > 0; o >>= 1) x = fmaxf(x, __shfl_down(x, o));
    __shared__ float r[8];
    const int tx = threadIdx.x;
    if ((tx & 63) == 0) r[tx >> 6] = x;
    __syncthreads();
    x = fmaxf(fmaxf(fmaxf(r[0], r[1]), fmaxf(r[2], r[3])),
              fmaxf(fmaxf(r[4], r[5]), fmaxf(r[6], r[7])));
    __syncthreads();
    return x;
}

// One row: sum KS parts -> G, softmax VJP, Adam update, next softmax.
// grid 128, block 512 (4 cols/thread).
__global__ __launch_bounds__(512)
void adam_kernel(const float* __restrict__ parts, const float* __restrict__ Bm,
                 float* __restrict__ W, float* __restrict__ P,
                 float* __restrict__ M, float* __restrict__ V,
                 const float bc1, const float bc2)
{
    const int i = blockIdx.x;
    const int tx = threadIdx.x;
    const int base = i * DN + tx * 4;

    float4 s = {0.f, 0.f, 0.f, 0.f};
    #pragma unroll
    for (int p = 0; p < KS; ++p) {
        const float4 x = *(const float4*)&parts[(size_t)p * (NT * DN) + base];
        s.x += x.x; s.y += x.y; s.z += x.z; s.w += x.w;
    }
    const float4 b = *(const float4*)&Bm[base];
    float G4[4] = { 2.f * (s.x - b.x), 2.f * (s.y - b.y),
                    2.f * (s.z - b.z), 2.f * (s.w - b.w) };

    float W4[4], P4[4], M4[4], V4[4], E4[4];
    *(float4*)&W4[0] = *(const float4*)&W[base];

    float sp = 0.f;
    #pragma unroll
    for (int e = 0; e < 4; ++e) sp += W4[e] * G4[e];
    const float srow = blk_sum(sp);

    *(float4*)&P4[0] = *(const float4*)&P[base];
    *(float4*)&M4[0] = *(const float4*)&M[base];
    *(float4*)&V4[0] = *(const float4*)&V[base];

    float mx = -1e30f;
    #pragma unroll
    for (int e = 0; e < 4; ++e) {
        const float g  = W4[e] * (G4[e] - srow);
        const float m_ = BETA1 * M4[e] + (1.f - BETA1) * g;
        const float v_ = BETA2 * V4[e] + (1.f - BETA2) * g * g;
        M4[e] = m_; V4[e] = v_;
        const float mh = m_ * bc1;
        const float vh = v_ * bc2;
        const float pn = P4[e] - LR * mh / (sqrtf(vh) + EPSA);
        P4[e] = pn;
        mx = fmaxf(mx, pn);
    }
    mx = blk_max(mx);

    float es = 0.f;
    #pragma unroll
    for (int e = 0; e < 4; ++e) { E4[e] = expf(P4[e] - mx); es += E4[e]; }
    const float sig = blk_sum(es);
    #pragma unroll
    for (int e = 0; e < 4; ++e) W4[e] = E4[e] / sig;

    *(float4*)&W[base] = *(const float4*)&W4[0];
    *(float4*)&P[base] = *(const float4*)&P4[0];
    *(float4*)&M[base] = *(const float4*)&M4[0];
    *(float4*)&V[base] = *(const float4*)&V4[0];
}

// ---------------------------------------------------------------------------
extern "C" void kernel_launch(void* const* d_in, const int* in_sizes, int n_in,
                              void* d_out, int out_size, void* d_ws, size_t ws_size,
                              hipStream_t stream)
{
    const float* H  = (const float*)d_in[0];   // [128][2048]
    const float* Ht = (const float*)d_in[1];   // [2048][2048]

    float* ws = (float*)d_ws;
    float* A     = ws;                          // 2048*2048        (16 MB)
    float* Bm    = A  + (size_t)DN * DN;        // 128*2048
    float* P     = Bm + (size_t)NT * DN;
    float* M     = P  + (size_t)NT * DN;
    float* V     = M  + (size_t)NT * DN;
    float* W     = V  + (size_t)NT * DN;
    float* parts = W  + (size_t)NT * DN;        // KS * 128*2048    (16 MB)

    // One-time precompute
    gram_kernel<<<dim3(32, 32), 256, 0, stream>>>(Ht, A);            // A = Ht Ht^T
    bpart_kernel<<<dim3(64, 4), 512, 0, stream>>>(H, Ht, parts);     // H Ht^T partials (4 slices)
    sumB_kernel<<<256, 256, 0, stream>>>(parts, Bm);                 // B = H Ht^T
    init_kernel<<<256, 256, 0, stream>>>(P, M, V, W);                // P=m=v=0, W=1/2048

    double b1t = 1.0, b2t = 1.0;
    for (int t = 1; t <= 1000; ++t) {
        b1t *= 0.9; b2t *= 0.999;
        wa_kernel<<<dim3(DN / CB, NT / RB, KS), 256, 0, stream>>>(W, A, parts);
        const float bc1 = (float)(1.0 / (1.0 - b1t));
        const float bc2 = (float)(1.0 / (1.0 - b2t));
        adam_kernel<<<NT, 512, 0, stream>>>(parts, Bm, W, P, M, V, bc1, bc2);
    }

    hipMemcpyAsync(d_out, W, (size_t)NT * DN * sizeof(float),
                   hipMemcpyDeviceToDevice, stream);
}